// Round 5
// baseline (26.799 us; speedup 1.0000x reference)
//
#include <hip/hip_runtime.h>
#include <cfloat>

// Problem constants (fixed by the reference)
#define N_PTS 65536
#define M_PTS 1024
#define WAVES 16
#define BLOCK (WAVES * 64)          // 1024 threads
#define QPB   128                   // queries per block (2 per lane)
#define CHUNK (M_PTS / WAVES)       // 64 maze points per wave

typedef float f32x2 __attribute__((ext_vector_type(2)));
typedef float f32x4 __attribute__((ext_vector_type(4)));

// Constraints satisfied simultaneously (R1-R3 each violated one):
//  - LDS pipe: 2 queries/lane halves broadcast ds_read count vs 1 q/lane
//    (393K b128 total ~= 7.7us < 9.4us VALU floor)
//  - occupancy: 512 blocks x 16 waves = 8 waves/SIMD (max for latency hiding)
//  - prefetch: manual 2-stage register pipeline on maze tiles
// All f32 math exact (contract off, reference op order: diff, square,
// (dx2+dy2)+dz2, sequential) -> bit-identical distances -> exact argmin.
__global__ __launch_bounds__(BLOCK, 8) void linearize_kernel(
    const float* __restrict__ ed,   // [N,3] euclidean_data
    const float* __restrict__ mp,   // [M,3] maze_points
    const float* __restrict__ ts,   // [M]   ts_proj
    float* __restrict__ out)        // [N*3] projected_pos ++ [N] linear_pos
{
#pragma clang fp contract(off)
    __shared__ float soa[3][M_PTS];     // 12 KB maze SoA
    __shared__ float s_d[WAVES][QPB];   //  8 KB candidate distances
    __shared__ int   s_i[WAVES][QPB];   //  8 KB candidate indices

    const int tid = threadIdx.x;

    // Stage maze AoS->SoA (3072 coalesced dwords, 3 per thread).
    #pragma unroll
    for (int j = tid; j < 3 * M_PTS; j += BLOCK) {
        soa[j % 3][j / 3] = mp[j];
    }

    const int lane = tid & 63;
    const int w = __builtin_amdgcn_readfirstlane(tid >> 6);
    const int q0 = blockIdx.x * QPB + lane * 2;     // this lane's 2 queries

    // 24 B/lane, 8-aligned -> 3 x dwordx2, fully coalesced.
    const f32x2 e0 = *(const f32x2*)&ed[q0 * 3 + 0];   // qa.xy
    const f32x2 e1 = *(const f32x2*)&ed[q0 * 3 + 2];   // qa.z qb.x
    const f32x2 e2 = *(const f32x2*)&ed[q0 * 3 + 4];   // qb.yz
    const float ax = e0.x, ay = e0.y, az = e1.x;
    const float bx = e1.y, by = e2.x, bz = e2.y;

    __syncthreads();

    float da = FLT_MAX, db = FLT_MAX;
    int   ia = 0, ib = 0;
    const int m0 = w * CHUNK;

    // Manual 2-stage pipeline: load tile t+1 while computing tile t.
    f32x4 cx = *(const f32x4*)&soa[0][m0];
    f32x4 cy = *(const f32x4*)&soa[1][m0];
    f32x4 cz = *(const f32x4*)&soa[2][m0];

    #pragma unroll
    for (int t = 0; t < CHUNK / 4; ++t) {
        f32x4 nx, ny, nz;
        if (t + 1 < CHUNK / 4) {
            const int m = m0 + (t + 1) * 4;
            nx = *(const f32x4*)&soa[0][m];
            ny = *(const f32x4*)&soa[1][m];
            nz = *(const f32x4*)&soa[2][m];
        }
        const int mt = m0 + t * 4;
        // 8 independent select chains (2 queries x 4 points) per tile.
        #define STEP(T) do {                                               \
            const float px = cx[T], py = cy[T], pz = cz[T];                \
            const float dxa = ax - px, dya = ay - py, dza = az - pz;       \
            const float dda = (dxa * dxa + dya * dya) + dza * dza;         \
            const float dxb = bx - px, dyb = by - py, dzb = bz - pz;       \
            const float ddb = (dxb * dxb + dyb * dyb) + dzb * dzb;         \
            if (dda < da) { da = dda; ia = mt + T; }                       \
            if (ddb < db) { db = ddb; ib = mt + T; }                       \
        } while (0)
        STEP(0); STEP(1); STEP(2); STEP(3);
        #undef STEP
        cx = nx; cy = ny; cz = nz;
    }

    s_d[w][lane * 2 + 0] = da;  s_i[w][lane * 2 + 0] = ia;
    s_d[w][lane * 2 + 1] = db;  s_i[w][lane * 2 + 1] = ib;
    __syncthreads();

    // Merge the 16 per-wave candidates per query (ascending chunk ranges,
    // strict '<' + index tie-break -> global first-argmin, jnp semantics).
    if (tid < QPB) {
        float dmin = s_d[0][tid];
        int   best = s_i[0][tid];
        #pragma unroll
        for (int j = 1; j < WAVES; ++j) {
            const float od = s_d[j][tid];
            const int   ob = s_i[j][tid];
            if (od < dmin || (od == dmin && ob < best)) { dmin = od; best = ob; }
        }
        const int i = blockIdx.x * QPB + tid;
        out[i * 3 + 0]     = soa[0][best];
        out[i * 3 + 1]     = soa[1][best];
        out[i * 3 + 2]     = soa[2][best];
        out[N_PTS * 3 + i] = ts[best];
    }
}

extern "C" void kernel_launch(void* const* d_in, const int* in_sizes, int n_in,
                              void* d_out, int out_size, void* d_ws, size_t ws_size,
                              hipStream_t stream) {
    const float* ed = (const float*)d_in[0];
    const float* mp = (const float*)d_in[1];
    const float* ts = (const float*)d_in[2];
    float* out = (float*)d_out;

    const int grid = N_PTS / QPB;   // 512 blocks x 1024 threads = 8192 waves
    linearize_kernel<<<grid, BLOCK, 0, stream>>>(ed, mp, ts, out);
}

// Round 6
// 24.460 us; speedup vs baseline: 1.0956x; 1.0956x over previous
//
#include <hip/hip_runtime.h>
#include <cfloat>

// Problem constants (fixed by the reference)
#define N_PTS 65536
#define M_PTS 1024
#define WAVES 16
#define BLOCK (WAVES * 64)          // 1024 threads
#define QPB   128                   // queries per block (2 per lane)
#define CHUNK (M_PTS / WAVES)       // 64 maze points per wave

typedef float f32x4 __attribute__((ext_vector_type(4)));

// Lessons R1-R4: (a) LDS broadcast traffic must be amortized (q=2/lane ->
// 7.7us DS pipe); (b) manual pipelining + min-waves launch_bounds caused
// VGPR spills (R4 regression) -> keep live state tiny, let the compiler
// schedule; (c) ext-vector packing adds moves (R3) -> scalar math; (d) full
// unroll makes all LDS offsets immediates and all local indices inline
// constants (0..63 are free VOP3 constants) -> zero index/address arithmetic.
// All f32 math exact (contract off, reference op order) -> bit-identical
// distances -> exact argmin with ascending-index tie-breaks everywhere.
__global__ __launch_bounds__(BLOCK) void linearize_kernel(
    const float* __restrict__ ed,   // [N,3] euclidean_data
    const float* __restrict__ mp,   // [M,3] maze_points
    const float* __restrict__ ts,   // [M]   ts_proj
    float* __restrict__ out)        // [N*3] projected_pos ++ [N] linear_pos
{
#pragma clang fp contract(off)
    __shared__ float soa[3][M_PTS];     // 12 KB maze SoA
    __shared__ float s_d[WAVES][QPB];   //  8 KB candidate distances
    __shared__ int   s_i[WAVES][QPB];   //  8 KB candidate indices

    const int tid = threadIdx.x;

    // Stage maze AoS->SoA (3072 coalesced dwords, 3 per thread).
    #pragma unroll
    for (int j = tid; j < 3 * M_PTS; j += BLOCK) {
        soa[j % 3][j / 3] = mp[j];
    }

    const int lane = tid & 63;
    const int w = tid >> 6;
    const int q0 = blockIdx.x * QPB + lane * 2;     // this lane's 2 queries

    // 24 B/lane contiguous -> coalesced dwordx2 loads.
    const float ax = ed[q0 * 3 + 0], ay = ed[q0 * 3 + 1], az = ed[q0 * 3 + 2];
    const float bx = ed[q0 * 3 + 3], by = ed[q0 * 3 + 4], bz = ed[q0 * 3 + 5];

    __syncthreads();

    float da = FLT_MAX, db = FLT_MAX;
    int   la = 0, lb = 0;               // local index within chunk (0..63)
    const int m0 = w * CHUNK;

    // FULL unroll: k+T are compile-time constants -> inline-const cndmask
    // operands and immediate LDS offsets; no address or index arithmetic.
    #pragma unroll
    for (int k = 0; k < CHUNK; k += 4) {
        const f32x4 px = *(const f32x4*)&soa[0][m0 + k];
        const f32x4 py = *(const f32x4*)&soa[1][m0 + k];
        const f32x4 pz = *(const f32x4*)&soa[2][m0 + k];
        #pragma unroll
        for (int T = 0; T < 4; ++T) {
            const float pxx = px[T], pyy = py[T], pzz = pz[T];
            const float dxa = ax - pxx, dya = ay - pyy, dza = az - pzz;
            const float dda = (dxa * dxa + dya * dya) + dza * dza;
            const float dxb = bx - pxx, dyb = by - pyy, dzb = bz - pzz;
            const float ddb = (dxb * dxb + dyb * dyb) + dzb * dzb;
            if (dda < da) { da = dda; la = k + T; }   // k+T inline const
            if (ddb < db) { db = ddb; lb = k + T; }
        }
    }

    s_d[w][lane * 2 + 0] = da;  s_i[w][lane * 2 + 0] = m0 + la;
    s_d[w][lane * 2 + 1] = db;  s_i[w][lane * 2 + 1] = m0 + lb;
    __syncthreads();

    // Merge the 16 per-wave candidates per query (ascending chunk ranges,
    // strict '<' + index tie-break -> global first-argmin, jnp semantics).
    if (tid < QPB) {
        float dmin = s_d[0][tid];
        int   best = s_i[0][tid];
        #pragma unroll
        for (int j = 1; j < WAVES; ++j) {
            const float od = s_d[j][tid];
            const int   ob = s_i[j][tid];
            if (od < dmin || (od == dmin && ob < best)) { dmin = od; best = ob; }
        }
        const int i = blockIdx.x * QPB + tid;
        out[i * 3 + 0]     = soa[0][best];
        out[i * 3 + 1]     = soa[1][best];
        out[i * 3 + 2]     = soa[2][best];
        out[N_PTS * 3 + i] = ts[best];
    }
}

extern "C" void kernel_launch(void* const* d_in, const int* in_sizes, int n_in,
                              void* d_out, int out_size, void* d_ws, size_t ws_size,
                              hipStream_t stream) {
    const float* ed = (const float*)d_in[0];
    const float* mp = (const float*)d_in[1];
    const float* ts = (const float*)d_in[2];
    float* out = (float*)d_out;

    const int grid = N_PTS / QPB;   // 512 blocks x 1024 threads = 8192 waves
    linearize_kernel<<<grid, BLOCK, 0, stream>>>(ed, mp, ts, out);
}

// Round 7
// 24.380 us; speedup vs baseline: 1.0992x; 1.0033x over previous
//
#include <hip/hip_runtime.h>
#include <cfloat>

// Problem constants (fixed by the reference)
#define N_PTS 65536
#define M_PTS 1024
#define WAVES 16
#define BLOCK 1024
#define QPB   256      // queries per block (4 per lane)
#define P     32       // maze points per wave
#define HALF  512      // maze points per block (half of M)

typedef float f32x4 __attribute__((ext_vector_type(4)));

// Occupancy identity: waves = Q*Msplit/(64*q). q=4 & 8192 waves (8/SIMD)
// forces Msplit=32, which cannot merge in one 1024-thread block -> split M
// in half per block (blockIdx = qgroup*2 + half) and merge the two halves
// in a tiny second kernel via workspace. LDS broadcast traffic: 8192 waves
// x 24 ds_read_b128 = 196K (~3.9us) - far below the VALU floor. VGPR kept
// lean (~55) so __launch_bounds__(1024,8) yields 2 blocks/CU without spill.
// All f32 math exact (contract off, reference op order) -> bit-identical
// distances; strict '<' + smaller-index tie-breaks at every level -> exact
// jnp.argmin semantics (order-independent).
__global__ __launch_bounds__(BLOCK, 8) void nn_partial(
    const float* __restrict__ ed,     // [N,3]
    const float* __restrict__ mp,     // [M,3]
    float* __restrict__ dpart,        // [512*256] per-(block,query) best dist
    int*   __restrict__ ipart)        // [512*256] per-(block,query) best idx
{
#pragma clang fp contract(off)
    __shared__ float soa[3][HALF];      // 6 KB maze half, SoA
    __shared__ float s_d[WAVES][QPB];   // 16 KB
    __shared__ int   s_i[WAVES][QPB];   // 16 KB

    const int tid  = threadIdx.x;
    const int qg   = blockIdx.x >> 1;   // query group (256 queries)
    const int half = blockIdx.x & 1;    // which 512-pt maze half

    // Stage this block's maze half AoS->SoA (1536 coalesced dwords).
    #pragma unroll
    for (int j = tid; j < 3 * HALF; j += BLOCK) {
        soa[j % 3][j / 3] = mp[half * (3 * HALF) + j];
    }

    const int lane = tid & 63;
    const int w = tid >> 6;
    const int q0 = qg * QPB + lane * 4;   // this lane's 4 queries

    // 48 B/lane contiguous, 16B-aligned -> 3 x dwordx4 coalesced.
    const f32x4 e0 = *(const f32x4*)&ed[q0 * 3 + 0];  // qa.xyz qb.x
    const f32x4 e1 = *(const f32x4*)&ed[q0 * 3 + 4];  // qb.yz  qc.xy
    const f32x4 e2 = *(const f32x4*)&ed[q0 * 3 + 8];  // qc.z   qd.xyz
    const float ax = e0.x, ay = e0.y, az = e0.z;
    const float bx = e0.w, by = e1.x, bz = e1.y;
    const float cx = e1.z, cy = e1.w, cz = e2.x;
    const float qx = e2.y, qy = e2.z, qz = e2.w;

    __syncthreads();

    float dA = FLT_MAX, dB = FLT_MAX, dC = FLT_MAX, dD = FLT_MAX;
    int   iA = 0, iB = 0, iC = 0, iD = 0;
    const int lbase = w * P;                 // LDS base for this wave
    const int gbase = half * HALF + lbase;   // global maze index base (SGPR)

    #pragma unroll 2
    for (int k = 0; k < P; k += 4) {
        const f32x4 px = *(const f32x4*)&soa[0][lbase + k];
        const f32x4 py = *(const f32x4*)&soa[1][lbase + k];
        const f32x4 pz = *(const f32x4*)&soa[2][lbase + k];
        #pragma unroll
        for (int T = 0; T < 4; ++T) {
            const float mx = px[T], my = py[T], mz = pz[T];
            const int gi = gbase + k + T;    // uniform SGPR + inline const
            {
                const float t0 = ax - mx, t1 = ay - my, t2 = az - mz;
                const float dd = (t0 * t0 + t1 * t1) + t2 * t2;
                if (dd < dA) { dA = dd; iA = gi; }
            }
            {
                const float t0 = bx - mx, t1 = by - my, t2 = bz - mz;
                const float dd = (t0 * t0 + t1 * t1) + t2 * t2;
                if (dd < dB) { dB = dd; iB = gi; }
            }
            {
                const float t0 = cx - mx, t1 = cy - my, t2 = cz - mz;
                const float dd = (t0 * t0 + t1 * t1) + t2 * t2;
                if (dd < dC) { dC = dd; iC = gi; }
            }
            {
                const float t0 = qx - mx, t1 = qy - my, t2 = qz - mz;
                const float dd = (t0 * t0 + t1 * t1) + t2 * t2;
                if (dd < dD) { dD = dd; iD = gi; }
            }
        }
    }

    s_d[w][lane * 4 + 0] = dA;  s_i[w][lane * 4 + 0] = iA;
    s_d[w][lane * 4 + 1] = dB;  s_i[w][lane * 4 + 1] = iB;
    s_d[w][lane * 4 + 2] = dC;  s_i[w][lane * 4 + 2] = iC;
    s_d[w][lane * 4 + 3] = dD;  s_i[w][lane * 4 + 3] = iD;
    __syncthreads();

    // Merge 16 per-wave candidates per query; order-independent tie-break.
    if (tid < QPB) {
        float dm = s_d[0][tid];
        int   bi = s_i[0][tid];
        #pragma unroll
        for (int j = 1; j < WAVES; ++j) {
            const float od = s_d[j][tid];
            const int   ob = s_i[j][tid];
            if (od < dm || (od == dm && ob < bi)) { dm = od; bi = ob; }
        }
        const int slot = blockIdx.x * QPB + tid;   // (qg*2+half)*256+tid
        dpart[slot] = dm;
        ipart[slot] = bi;
    }
}

// Merge the two maze-halves per query and gather outputs.
__global__ __launch_bounds__(256) void nn_final(
    const float* __restrict__ mp,
    const float* __restrict__ ts,
    const float* __restrict__ dpart,
    const int*   __restrict__ ipart,
    float* __restrict__ out)
{
    const int q = blockIdx.x * 256 + threadIdx.x;   // global query id
    const int g = q >> 8, r = q & 255;
    const float d0 = dpart[(g * 2 + 0) * QPB + r];
    const float d1 = dpart[(g * 2 + 1) * QPB + r];
    const int   i0 = ipart[(g * 2 + 0) * QPB + r];
    const int   i1 = ipart[(g * 2 + 1) * QPB + r];
    // half-0 indices are all smaller than half-1's -> on tie keep i0.
    const int best = (d1 < d0) ? i1 : i0;
    out[q * 3 + 0]     = mp[best * 3 + 0];
    out[q * 3 + 1]     = mp[best * 3 + 1];
    out[q * 3 + 2]     = mp[best * 3 + 2];
    out[N_PTS * 3 + q] = ts[best];
}

extern "C" void kernel_launch(void* const* d_in, const int* in_sizes, int n_in,
                              void* d_out, int out_size, void* d_ws, size_t ws_size,
                              hipStream_t stream) {
    const float* ed = (const float*)d_in[0];
    const float* mp = (const float*)d_in[1];
    const float* ts = (const float*)d_in[2];
    float* out = (float*)d_out;

    float* dpart = (float*)d_ws;                       // 512*256 floats
    int*   ipart = (int*)d_ws + 512 * QPB;             // 512*256 ints (1 MB total)

    const int grid1 = (N_PTS / QPB) * 2;   // 512 blocks (qgroup x half)
    nn_partial<<<grid1, BLOCK, 0, stream>>>(ed, mp, dpart, ipart);

    const int grid2 = N_PTS / 256;         // 256 blocks
    nn_final<<<grid2, 256, 0, stream>>>(mp, ts, dpart, ipart, out);
}

// Round 8
// 23.028 us; speedup vs baseline: 1.1638x; 1.0587x over previous
//
#include <hip/hip_runtime.h>
#include <cfloat>

// Problem constants (fixed by the reference)
#define N_PTS 65536
#define M_PTS 1024
#define WAVES 8
#define BLOCK 512      // 8 waves — measured 3 us faster than 1024-thr blocks
#define QPB   128      // queries per block (2 per lane)
#define HALF  512      // maze points per block (half of M)
#define CHUNK 64       // maze points per wave (HALF / WAVES)

typedef float f32x2 __attribute__((ext_vector_type(2)));
typedef float f32x4 __attribute__((ext_vector_type(4)));

// Evidence through R7: 512-thr blocks beat 1024-thr blocks (R2 21.75 vs
// R5/R6/R7 24.4+) and cross-block merge via ws is free (R6 vs R7). This
// kernel combines q=2/lane (LDS pipe 7.7us, below VALU floor) with 512-thr
// blocks by splitting the maze across 2 blocks per query group:
//   blockIdx = qgroup*2 + half;  8 waves x 64-pt chunk = 512-pt half.
// 1024 blocks x 8 waves = 8192 waves = 8/SIMD; ~35 VGPR, 14KB LDS ->
// 4 blocks/CU. All f32 math exact (contract off, reference op order:
// diff, square, (dx2+dy2)+dz2) -> bit-identical distances; strict '<' +
// ascending-index tie-breaks at every merge level -> exact jnp.argmin.
__global__ __launch_bounds__(BLOCK) void nn_partial(
    const float* __restrict__ ed,     // [N,3]
    const float* __restrict__ mp,     // [M,3]
    float* __restrict__ dpart,        // [1024*128] per-(block,query) best dist
    int*   __restrict__ ipart)        // [1024*128] per-(block,query) best idx
{
#pragma clang fp contract(off)
    __shared__ float soa[3][HALF];      // 6 KB maze half, SoA
    __shared__ float s_d[WAVES][QPB];   // 4 KB
    __shared__ int   s_i[WAVES][QPB];   // 4 KB

    const int tid  = threadIdx.x;
    const int qg   = blockIdx.x >> 1;   // query group (128 queries)
    const int half = blockIdx.x & 1;    // which 512-pt maze half

    // Stage this block's maze half AoS->SoA (1536 coalesced dwords, 3/thread).
    #pragma unroll
    for (int j = tid; j < 3 * HALF; j += BLOCK) {
        soa[j % 3][j / 3] = mp[half * (3 * HALF) + j];
    }

    const int lane = tid & 63;
    const int w = tid >> 6;
    const int q0 = qg * QPB + lane * 2;     // this lane's 2 queries

    // 24 B/lane contiguous (8-aligned) -> 3 x dwordx2 coalesced.
    const f32x2 e0 = *(const f32x2*)&ed[q0 * 3 + 0];   // qa.xy
    const f32x2 e1 = *(const f32x2*)&ed[q0 * 3 + 2];   // qa.z qb.x
    const f32x2 e2 = *(const f32x2*)&ed[q0 * 3 + 4];   // qb.yz
    const float ax = e0.x, ay = e0.y, az = e1.x;
    const float bx = e1.y, by = e2.x, bz = e2.y;

    __syncthreads();

    float da = FLT_MAX, db = FLT_MAX;
    int   la = 0, lb = 0;               // local index within chunk (0..63)
    const int lbase = w * CHUNK;        // LDS element base for this wave

    // k, T compile-time after unroll -> immediate LDS offsets and inline-
    // constant (0..63) cndmask sources; no index arithmetic in the loop.
    #pragma unroll
    for (int k = 0; k < CHUNK; k += 4) {
        const f32x4 px = *(const f32x4*)&soa[0][lbase + k];
        const f32x4 py = *(const f32x4*)&soa[1][lbase + k];
        const f32x4 pz = *(const f32x4*)&soa[2][lbase + k];
        #pragma unroll
        for (int T = 0; T < 4; ++T) {
            const float mx = px[T], my = py[T], mz = pz[T];
            const float t0 = ax - mx, t1 = ay - my, t2 = az - mz;
            const float dda = (t0 * t0 + t1 * t1) + t2 * t2;
            const float u0 = bx - mx, u1 = by - my, u2 = bz - mz;
            const float ddb = (u0 * u0 + u1 * u1) + u2 * u2;
            if (dda < da) { da = dda; la = k + T; }
            if (ddb < db) { db = ddb; lb = k + T; }
        }
    }

    // Convert to global maze index: half*512 + w*64 + local.
    const int gbase = half * HALF + lbase;
    s_d[w][lane * 2 + 0] = da;  s_i[w][lane * 2 + 0] = gbase + la;
    s_d[w][lane * 2 + 1] = db;  s_i[w][lane * 2 + 1] = gbase + lb;
    __syncthreads();

    // Merge the 8 per-wave candidates per query (ascending chunk ranges,
    // strict '<' + index tie-break -> first-argmin within this half).
    if (tid < QPB) {
        float dm = s_d[0][tid];
        int   bi = s_i[0][tid];
        #pragma unroll
        for (int j = 1; j < WAVES; ++j) {
            const float od = s_d[j][tid];
            const int   ob = s_i[j][tid];
            if (od < dm || (od == dm && ob < bi)) { dm = od; bi = ob; }
        }
        const int slot = blockIdx.x * QPB + tid;
        dpart[slot] = dm;
        ipart[slot] = bi;
    }
}

// Merge the two maze-halves per query and gather outputs (proven ~free, R7).
__global__ __launch_bounds__(256) void nn_final(
    const float* __restrict__ mp,
    const float* __restrict__ ts,
    const float* __restrict__ dpart,
    const int*   __restrict__ ipart,
    float* __restrict__ out)
{
    const int q = blockIdx.x * 256 + threadIdx.x;   // global query id
    const int g = q >> 7, r = q & 127;              // query group, offset
    const float d0 = dpart[(g * 2 + 0) * QPB + r];
    const float d1 = dpart[(g * 2 + 1) * QPB + r];
    const int   i0 = ipart[(g * 2 + 0) * QPB + r];
    const int   i1 = ipart[(g * 2 + 1) * QPB + r];
    // half-0 indices are all smaller than half-1's -> on tie keep i0.
    const int best = (d1 < d0) ? i1 : i0;
    out[q * 3 + 0]     = mp[best * 3 + 0];
    out[q * 3 + 1]     = mp[best * 3 + 1];
    out[q * 3 + 2]     = mp[best * 3 + 2];
    out[N_PTS * 3 + q] = ts[best];
}

extern "C" void kernel_launch(void* const* d_in, const int* in_sizes, int n_in,
                              void* d_out, int out_size, void* d_ws, size_t ws_size,
                              hipStream_t stream) {
    const float* ed = (const float*)d_in[0];
    const float* mp = (const float*)d_in[1];
    const float* ts = (const float*)d_in[2];
    float* out = (float*)d_out;

    float* dpart = (float*)d_ws;                     // 1024*128 floats (512 KB)
    int*   ipart = (int*)d_ws + 1024 * QPB;          // 1024*128 ints  (512 KB)

    const int grid1 = (N_PTS / QPB) * 2;   // 1024 blocks (qgroup x half)
    nn_partial<<<grid1, BLOCK, 0, stream>>>(ed, mp, dpart, ipart);

    const int grid2 = N_PTS / 256;         // 256 blocks
    nn_final<<<grid2, 256, 0, stream>>>(mp, ts, dpart, ipart, out);
}

// Round 9
// 22.197 us; speedup vs baseline: 1.2073x; 1.0374x over previous
//
#include <hip/hip_runtime.h>
#include <cfloat>

// Problem constants (fixed by the reference)
#define N_PTS 65536
#define M_PTS 1024
#define WAVES 8
#define BLOCK 512      // 8 waves — measured faster than 1024-thr blocks
#define QPB   128      // queries per block (2 per lane)
#define HALF  512      // maze points per block (half of M)
#define CHUNK 64       // maze points per wave (HALF / WAVES)

typedef float f32x2 __attribute__((ext_vector_type(2)));
typedef float f32x4 __attribute__((ext_vector_type(4)));

// Forced VOP3P packed-f32 (CDNA2+ "packed FP32"): 2 maze points per
// instruction. Inline asm guarantees pk emission (compiler may otherwise
// scalarize ext-vector float math). (m-q) vs (q-m): sign flip is exact and
// squared away -> distances bit-identical to the reference order
// (dx*dx + dy*dy) + dz*dz with contraction off.
#define PK_SUB(d, a, b) asm("v_pk_add_f32 %0, %1, %2 neg_lo:[0,1] neg_hi:[0,1]" : "=v"(d) : "v"(a), "v"(b))
#define PK_MUL(d, a, b) asm("v_pk_mul_f32 %0, %1, %2" : "=v"(d) : "v"(a), "v"(b))
#define PK_ADD(d, a, b) asm("v_pk_add_f32 %0, %1, %2" : "=v"(d) : "v"(a), "v"(b))

__global__ __launch_bounds__(BLOCK) void nn_partial(
    const float* __restrict__ ed,     // [N,3]
    const float* __restrict__ mp,     // [M,3]
    float* __restrict__ dpart,        // [1024*128] per-(block,query) best dist
    int*   __restrict__ ipart)        // [1024*128] per-(block,query) best idx
{
#pragma clang fp contract(off)
    __shared__ float soa[3][HALF];      // 6 KB maze half, SoA
    __shared__ float s_d[WAVES][QPB];   // 4 KB
    __shared__ int   s_i[WAVES][QPB];   // 4 KB

    const int tid  = threadIdx.x;
    const int qg   = blockIdx.x >> 1;   // query group (128 queries)
    const int half = blockIdx.x & 1;    // which 512-pt maze half

    // Stage this block's maze half AoS->SoA (1536 coalesced dwords).
    #pragma unroll
    for (int j = tid; j < 3 * HALF; j += BLOCK) {
        soa[j % 3][j / 3] = mp[half * (3 * HALF) + j];
    }

    const int lane = tid & 63;
    const int w = tid >> 6;
    const int q0 = qg * QPB + lane * 2;     // this lane's 2 queries

    const f32x2 e0 = *(const f32x2*)&ed[q0 * 3 + 0];   // qa.xy
    const f32x2 e1 = *(const f32x2*)&ed[q0 * 3 + 2];   // qa.z qb.x
    const f32x2 e2 = *(const f32x2*)&ed[q0 * 3 + 4];   // qb.yz

    // Broadcast pairs, built once (12 VGPRs): {q,q} per coord per query.
    const f32x2 qax = {e0.x, e0.x}, qay = {e0.y, e0.y}, qaz = {e1.x, e1.x};
    const f32x2 qbx = {e1.y, e1.y}, qby = {e2.x, e2.x}, qbz = {e2.y, e2.y};

    __syncthreads();

    float da = FLT_MAX, db = FLT_MAX;
    int   la = 0, lb = 0;               // local index within chunk (0..63)
    const int lbase = w * CHUNK;        // LDS element base for this wave

    // Full unroll: immediate LDS offsets; k+T inline-constant cndmask srcs.
    #pragma unroll
    for (int k = 0; k < CHUNK; k += 4) {
        const f32x4 px = *(const f32x4*)&soa[0][lbase + k];
        const f32x4 py = *(const f32x4*)&soa[1][lbase + k];
        const f32x4 pz = *(const f32x4*)&soa[2][lbase + k];
        // Maze-axis pairs: .xy/.zw of the b128 result are even-aligned
        // VGPR pairs already -> zero packing movs.
        #pragma unroll
        for (int P = 0; P < 2; ++P) {
            const f32x2 mx = (P == 0) ? f32x2{px.x, px.y} : f32x2{px.z, px.w};
            const f32x2 my = (P == 0) ? f32x2{py.x, py.y} : f32x2{py.z, py.w};
            const f32x2 mz = (P == 0) ? f32x2{pz.x, pz.y} : f32x2{pz.z, pz.w};
            f32x2 dx, dy, dz, sx, sy, sz, t, dA, dB;
            // Query a vs points {k+2P, k+2P+1}
            PK_SUB(dx, mx, qax); PK_SUB(dy, my, qay); PK_SUB(dz, mz, qaz);
            PK_MUL(sx, dx, dx); PK_MUL(sy, dy, dy); PK_MUL(sz, dz, dz);
            PK_ADD(t, sx, sy); PK_ADD(dA, t, sz);
            // Query b vs same points
            PK_SUB(dx, mx, qbx); PK_SUB(dy, my, qby); PK_SUB(dz, mz, qbz);
            PK_MUL(sx, dx, dx); PK_MUL(sy, dy, dy); PK_MUL(sz, dz, dz);
            PK_ADD(t, sx, sy); PK_ADD(dB, t, sz);
            // Ascending-order strict-'<' selects keep the first minimum.
            if (dA.x < da) { da = dA.x; la = k + 2 * P; }
            if (dA.y < da) { da = dA.y; la = k + 2 * P + 1; }
            if (dB.x < db) { db = dB.x; lb = k + 2 * P; }
            if (dB.y < db) { db = dB.y; lb = k + 2 * P + 1; }
        }
    }

    const int gbase = half * HALF + lbase;
    s_d[w][lane * 2 + 0] = da;  s_i[w][lane * 2 + 0] = gbase + la;
    s_d[w][lane * 2 + 1] = db;  s_i[w][lane * 2 + 1] = gbase + lb;
    __syncthreads();

    // Merge the 8 per-wave candidates per query (ascending chunk ranges,
    // strict '<' + index tie-break -> first-argmin within this half).
    if (tid < QPB) {
        float dm = s_d[0][tid];
        int   bi = s_i[0][tid];
        #pragma unroll
        for (int j = 1; j < WAVES; ++j) {
            const float od = s_d[j][tid];
            const int   ob = s_i[j][tid];
            if (od < dm || (od == dm && ob < bi)) { dm = od; bi = ob; }
        }
        const int slot = blockIdx.x * QPB + tid;
        dpart[slot] = dm;
        ipart[slot] = bi;
    }
}

// Merge the two maze-halves per query and gather outputs (proven ~free).
__global__ __launch_bounds__(256) void nn_final(
    const float* __restrict__ mp,
    const float* __restrict__ ts,
    const float* __restrict__ dpart,
    const int*   __restrict__ ipart,
    float* __restrict__ out)
{
    const int q = blockIdx.x * 256 + threadIdx.x;   // global query id
    const int g = q >> 7, r = q & 127;              // query group, offset
    const float d0 = dpart[(g * 2 + 0) * QPB + r];
    const float d1 = dpart[(g * 2 + 1) * QPB + r];
    const int   i0 = ipart[(g * 2 + 0) * QPB + r];
    const int   i1 = ipart[(g * 2 + 1) * QPB + r];
    // half-0 indices are all smaller than half-1's -> on tie keep i0.
    const int best = (d1 < d0) ? i1 : i0;
    out[q * 3 + 0]     = mp[best * 3 + 0];
    out[q * 3 + 1]     = mp[best * 3 + 1];
    out[q * 3 + 2]     = mp[best * 3 + 2];
    out[N_PTS * 3 + q] = ts[best];
}

extern "C" void kernel_launch(void* const* d_in, const int* in_sizes, int n_in,
                              void* d_out, int out_size, void* d_ws, size_t ws_size,
                              hipStream_t stream) {
    const float* ed = (const float*)d_in[0];
    const float* mp = (const float*)d_in[1];
    const float* ts = (const float*)d_in[2];
    float* out = (float*)d_out;

    float* dpart = (float*)d_ws;                     // 1024*128 floats (512 KB)
    int*   ipart = (int*)d_ws + 1024 * QPB;          // 1024*128 ints  (512 KB)

    const int grid1 = (N_PTS / QPB) * 2;   // 1024 blocks (qgroup x half)
    nn_partial<<<grid1, BLOCK, 0, stream>>>(ed, mp, dpart, ipart);

    const int grid2 = N_PTS / 256;         // 256 blocks
    nn_final<<<grid2, 256, 0, stream>>>(mp, ts, dpart, ipart, out);
}